// Round 1
// baseline (222.621 us; speedup 1.0000x reference)
//
#include <hip/hip_runtime.h>

// Hadamard on qubit TARGET=5 of N_QUBITS=24, batch=2, real float32 state.
// Per batch: L = 2^5 = 32, R = 2^18 = 262144.
// flat index = (b*L + l) * 2R + j*R + r ; pair stride = R floats.
// y0 = (x0 + x1) * inv_sqrt2 ; y1 = (x0 - x1) * inv_sqrt2.

__global__ __launch_bounds__(256) void hgate_kernel(const float4* __restrict__ x,
                                                    float4* __restrict__ y) {
    constexpr int R4_LOG2 = 16;                 // R/4 = 65536 float4 elements
    constexpr int R4 = 1 << R4_LOG2;
    const float s = 0.70710678118654752440f;

    int t = blockIdx.x * blockDim.x + threadIdx.x;   // t in [0, 2^22)
    int r4 = t & (R4 - 1);
    int bl = t >> R4_LOG2;                      // combined (batch, l) in [0, 64)
    int idx0 = (bl << (R4_LOG2 + 1)) + r4;      // bl * 2*R4 + r4
    int idx1 = idx0 + R4;

    float4 a = x[idx0];
    float4 c = x[idx1];

    float4 y0, y1;
    y0.x = (a.x + c.x) * s;  y1.x = (a.x - c.x) * s;
    y0.y = (a.y + c.y) * s;  y1.y = (a.y - c.y) * s;
    y0.z = (a.z + c.z) * s;  y1.z = (a.z - c.z) * s;
    y0.w = (a.w + c.w) * s;  y1.w = (a.w - c.w) * s;

    y[idx0] = y0;
    y[idx1] = y1;
}

extern "C" void kernel_launch(void* const* d_in, const int* in_sizes, int n_in,
                              void* d_out, int out_size, void* d_ws, size_t ws_size,
                              hipStream_t stream) {
    const float4* x = (const float4*)d_in[0];
    float4* y = (float4*)d_out;
    // total float4 pairs = 2 batches * 2^23 pairs / 4 = 2^22 threads
    const int total_threads = 1 << 22;
    const int block = 256;
    const int grid = total_threads / block;     // 16384
    hgate_kernel<<<grid, block, 0, stream>>>(x, y);
}